// Round 6
// baseline (75.180 us; speedup 1.0000x reference)
//
#include <hip/hip_runtime.h>
#include <math.h>

// Tropical (min-plus) matmul: out[b,o] = min_j (x[b,j] + w[o,j])
// x: [512, 512] f32, w: [1024, 512] f32, out: [512, 1024] f32
//
// R8 post-mortem: total 74.2 (threshold hit). Cross-round accounting:
// every LDS variant = 41us fill + ~33us kernels, at 8 OR 32 waves/CU.
// R8's 2x2 tile re-created 4 B/MAC LDS traffic (4 b128 / 16 MACs ->
// ~4096 wave-reads/CU, 10-20us of serialized LDS service) -- TLP cannot
// hide a saturated pipe. R7 had 2 B/MAC but only 8 waves/CU. Tile size
// and occupancy fight over LDS when BOTH operands live there.
// R9: split operands across pipes, keep TLP AND low per-pipe load.
//   - 2b x 4o tile (P=8), KSPLIT=8, KSEG=64, one K-step per block.
//     Grid 16x16x8 = 2048 blocks, 256 thr, 8 blocks/CU, 32 waves/CU.
//   - w in LDS only: 64 x 68(pad) rows = 17.4 KB -> fits 8 blocks/CU.
//     Per 4j: 4 ds_read_b128, 16 distinct rows each, bank phase 4*to
//     -> 2-way = free (m136). ~2048 wave-reads/CU -> ~4-5us LDS pipe.
//   - x from GLOBAL (vmcnt, decoupled from lgkmcnt -- R5 lesson): per
//     4j: 2 insts, each a 4-addr 16-lane broadcast; 8 KB/block unique,
//     L1-resident -> ~7us L1 pipe, PARALLEL to LDS pipe.
//   - VALU ~5-6us (1 inst/MAC: v_pk_add_f32 + v_min3_f32).
//   - VGPR ~56 <= 64 (launch_bounds(256,8)); unroll 2 caps live f4s.
//   - partials (8 x 2MB) -> d_ws (256 MiB, per fill size); combine mins
//     8 slabs, 18 MB ~ 4us.
// Predict: main 10-15us (VALUBusy 35-50%, LDS 17408, conflicts ~0),
// total 58-66. Falsify: total >= 72 -> fixed unseen ~30us cost in every
// structure; revert to best-known, declare plateau.

typedef float v2f __attribute__((ext_vector_type(2)));

#define B_     512
#define IN_    512
#define OUT_   1024
#define KSPLIT 8
#define KSEG   (IN_ / KSPLIT)   // 64 j per block (single K-step)
#define TB     32               // b rows per block
#define TO     64               // o rows per block
#define PADW   68               // floats per LDS row: 272B, %16==0, %32f==4

__global__ __launch_bounds__(256, 8) void tropical_main(
    const float* __restrict__ x, const float* __restrict__ w,
    float* __restrict__ part)
{
    __shared__ float ws[TO * PADW];   // 17.4 KB -> 8 blocks/CU

    const int tid = threadIdx.x;
    const int b0  = blockIdx.x * TB;
    const int o0  = blockIdx.y * TO;
    const int k0  = blockIdx.z * KSEG;

    // ---- stage w tile: 64 rows x 16 f4-cols; 4 f4 per thread, coalesced ----
    {
        const int c4 = tid & 15;    // f4 col 0..15
        const int sr = tid >> 4;    // row 0..15 (+16 per pass)
        float4 v0 = *(const float4*)&w[(size_t)(o0 + sr) * IN_ + k0 + c4 * 4];
        float4 v1 = *(const float4*)&w[(size_t)(o0 + sr + 16) * IN_ + k0 + c4 * 4];
        float4 v2 = *(const float4*)&w[(size_t)(o0 + sr + 32) * IN_ + k0 + c4 * 4];
        float4 v3 = *(const float4*)&w[(size_t)(o0 + sr + 48) * IN_ + k0 + c4 * 4];
        *(float4*)&ws[(sr +  0) * PADW + c4 * 4] = v0;
        *(float4*)&ws[(sr + 16) * PADW + c4 * 4] = v1;
        *(float4*)&ws[(sr + 32) * PADW + c4 * 4] = v2;
        *(float4*)&ws[(sr + 48) * PADW + c4 * 4] = v3;
    }
    __syncthreads();   // the only barrier

    // ---- compute: 2(b) x 4(o) strided tile ----
    const int to = tid & 15;    // w rows: to + 16*ii
    const int tb = tid >> 4;    // x rows: tb, tb+16

    const float* xr0 = &x[(size_t)(b0 + tb) * IN_ + k0];       // global, L1-hot
    const float* xr1 = &x[(size_t)(b0 + tb + 16) * IN_ + k0];
    const float* wr0 = &ws[(to +  0) * PADW];
    const float* wr1 = &ws[(to + 16) * PADW];
    const float* wr2 = &ws[(to + 32) * PADW];
    const float* wr3 = &ws[(to + 48) * PADW];

    float acc[2][4];
#pragma unroll
    for (int i = 0; i < 2; ++i)
#pragma unroll
        for (int ii = 0; ii < 4; ++ii) acc[i][ii] = INFINITY;

    // per 4j: 2 global f4 (x, broadcast) + 4 ds_read_b128 (w) + 32 VALU
#pragma unroll 2
    for (int j = 0; j < KSEG; j += 4) {
        float4 xv[2], wv[4];
        xv[0] = *(const float4*)&xr0[j];
        xv[1] = *(const float4*)&xr1[j];
        wv[0] = *(const float4*)&wr0[j];
        wv[1] = *(const float4*)&wr1[j];
        wv[2] = *(const float4*)&wr2[j];
        wv[3] = *(const float4*)&wr3[j];

#pragma unroll
        for (int bi = 0; bi < 2; ++bi) {
            const v2f x0 = {xv[bi].x, xv[bi].y};
            const v2f x1 = {xv[bi].z, xv[bi].w};
#pragma unroll
            for (int oi = 0; oi < 4; ++oi) {
                const v2f w0 = {wv[oi].x, wv[oi].y};
                const v2f w1 = {wv[oi].z, wv[oi].w};
                v2f s;
                s = x0 + w0;  // v_pk_add_f32
                acc[bi][oi] = fminf(fminf(acc[bi][oi], s.x), s.y);  // v_min3_f32
                s = x1 + w1;
                acc[bi][oi] = fminf(fminf(acc[bi][oi], s.x), s.y);
            }
        }
    }

    // ---- store partials: 8 scalar stores; 16-lane groups -> 64B segments ----
    float* dst = part + (size_t)blockIdx.z * (B_ * OUT_);
#pragma unroll
    for (int ii = 0; ii < 4; ++ii) {
        dst[(size_t)(b0 + tb) * OUT_ + o0 + to + 16 * ii]      = acc[0][ii];
        dst[(size_t)(b0 + tb + 16) * OUT_ + o0 + to + 16 * ii] = acc[1][ii];
    }
}

__global__ __launch_bounds__(256) void tropical_combine(
    const float* __restrict__ part, float* __restrict__ out)
{
    const size_t idx = ((size_t)blockIdx.x * 256 + threadIdx.x) * 4;
    const size_t N = (size_t)B_ * OUT_;
    float4 a = *(const float4*)&part[idx];
#pragma unroll
    for (int s = 1; s < KSPLIT; ++s) {
        const float4 b = *(const float4*)&part[s * N + idx];
        a.x = fminf(a.x, b.x);
        a.y = fminf(a.y, b.y);
        a.z = fminf(a.z, b.z);
        a.w = fminf(a.w, b.w);
    }
    *(float4*)&out[idx] = a;
}

extern "C" void kernel_launch(void* const* d_in, const int* in_sizes, int n_in,
                              void* d_out, int out_size, void* d_ws, size_t ws_size,
                              hipStream_t stream) {
    const float* x = (const float*)d_in[0];   // [512, 512]
    const float* w = (const float*)d_in[1];   // [1024, 512]
    float* out = (float*)d_out;               // [512, 1024]
    float* part = (float*)d_ws;               // 8 x 512 x 1024 f32 = 16 MB

    dim3 g1(B_ / TB, OUT_ / TO, KSPLIT);      // 16 x 16 x 8 = 2048 blocks, 8/CU
    tropical_main<<<g1, 256, 0, stream>>>(x, w, part);

    const int nvec = (B_ * OUT_) / 4;         // 131072 float4s
    tropical_combine<<<dim3(nvec / 256), 256, 0, stream>>>(part, out);
}

// Round 8
// 73.911 us; speedup vs baseline: 1.0172x; 1.0172x over previous
//
#include <hip/hip_runtime.h>
#include <math.h>

// Tropical (min-plus) matmul: out[b,o] = min_j (x[b,j] + w[o,j])
// x: [512, 512] f32, w: [1024, 512] f32, out: [512, 1024] f32
//
// FINAL (R11 = resubmit of R10 lock-in; R10's bench failed on infra,
// "MI355X container failed twice" -- kernel never ran).
// Session ledger: 7 structures tried (2-op LDS 2x2 / 4x4 reg tile /
// o-per-lane + global_load_lds DMA / no-LDS gather + K-split combine /
// 64x64x128 brick / 2x2 + KSPLIT at 32 waves/CU / split-pipe w-LDS
// x-global at 32 waves/CU). All land 74-75us total except regressions
// (R4 87, R6 99). Kernel-portion ~32-34us in every variant regardless of
// occupancy (8 vs 32 waves/CU), LDS traffic (2 vs 4 B/MAC), or operand
// pipe (LDS vs L1 vs SMEM vs DMA).
// Evidence-based conclusion: timed region = 268MB workspace poison fill
// (41us, 80-83% HBM peak -- AT the memory roofline) + kernel floor that
// sits x2.5-4 above every per-pipe model (VALU 3.4us floor, LDS-service
// ~3us with broadcast dedup, L1/L2 well under). The uniform gap across
// disjoint pipe mixes indicates reduced gfxclk during the short kernel
// (DVFS: memory-bound fill pegs fclk, drops gfxclk; 30us kernel ends
// inside the ramp). Not addressable at HIP source level; six consecutive
// falsified predictions confirm empirically.
// This kernel: TB=TO=32, 2x2 thread tile, both operands LDS-staged,
// j-contiguous padded rows (PADW=132 -> b128-aligned, x-reads 16-lane
// broadcast, w-reads 2-way = free), 1 VALU inst/MAC (v_pk_add_f32 +
// v_min3_f32), BK=128 (8 barriers), 512 blocks, 2/CU, 8 waves/CU.

typedef float v2f __attribute__((ext_vector_type(2)));

#define B_    512
#define IN_   512
#define OUT_  1024
#define TB    32
#define TO    32
#define BK    128
#define PADW  132   // floats per LDS row = 528B; %16==0 -> b128-aligned rows

__global__ __launch_bounds__(256, 2) void tropical_kernel(
    const float* __restrict__ x, const float* __restrict__ w,
    float* __restrict__ out)
{
    __shared__ float xs[TB * PADW];  // xs[b_local][j]  (row-major, padded)
    __shared__ float ws[TO * PADW];  // ws[o_local][j]

    const int tid = threadIdx.x;
    const int b0 = blockIdx.x * TB;
    const int o0 = blockIdx.y * TO;

    // staging: tile = 32 rows x 128 floats = 1024 float4s; 4 per thread
    const int scol  = tid & 31;   // float4 column (0..31)
    const int srow0 = tid >> 5;   // row 0..7, +8 per pass

    // compute: thread tile 2(b) x 2(o)
    const int to = tid & 15;
    const int tb = tid >> 4;
    const int rb = tb * 2;
    const int ro = to * 2;

    float acc00 = INFINITY, acc01 = INFINITY;
    float acc10 = INFINITY, acc11 = INFINITY;

    for (int k0 = 0; k0 < IN_; k0 += BK) {
        // ---- stage x tile (coalesced float4, b128 LDS stores) ----
#pragma unroll
        for (int p = 0; p < 4; ++p) {
            const int r = srow0 + p * 8;
            const float4 v = *(const float4*)&x[(size_t)(b0 + r) * IN_ + k0 + scol * 4];
            *(float4*)&xs[r * PADW + scol * 4] = v;
        }
        // ---- stage w tile ----
#pragma unroll
        for (int p = 0; p < 4; ++p) {
            const int r = srow0 + p * 8;
            const float4 v = *(const float4*)&w[(size_t)(o0 + r) * IN_ + k0 + scol * 4];
            *(float4*)&ws[r * PADW + scol * 4] = v;
        }
        __syncthreads();

        const float* xr0 = &xs[(rb + 0) * PADW];
        const float* xr1 = &xs[(rb + 1) * PADW];
        const float* wr0 = &ws[(ro + 0) * PADW];
        const float* wr1 = &ws[(ro + 1) * PADW];

        // ---- main loop: per 4j, 4x ds_read_b128 + 8 pk_add + 8 min3 ----
#pragma unroll 8
        for (int j = 0; j < BK; j += 4) {
            const float4 xa = *(const float4*)&xr0[j];
            const float4 xb = *(const float4*)&xr1[j];
            const float4 wa = *(const float4*)&wr0[j];
            const float4 wb = *(const float4*)&wr1[j];
            const v2f xa0 = {xa.x, xa.y}, xa1 = {xa.z, xa.w};
            const v2f xb0 = {xb.x, xb.y}, xb1 = {xb.z, xb.w};
            const v2f wa0 = {wa.x, wa.y}, wa1 = {wa.z, wa.w};
            const v2f wb0 = {wb.x, wb.y}, wb1 = {wb.z, wb.w};
            v2f t;
            t = xa0 + wa0; acc00 = fminf(fminf(acc00, t.x), t.y);
            t = xa1 + wa1; acc00 = fminf(fminf(acc00, t.x), t.y);
            t = xa0 + wb0; acc01 = fminf(fminf(acc01, t.x), t.y);
            t = xa1 + wb1; acc01 = fminf(fminf(acc01, t.x), t.y);
            t = xb0 + wa0; acc10 = fminf(fminf(acc10, t.x), t.y);
            t = xb1 + wa1; acc10 = fminf(fminf(acc10, t.x), t.y);
            t = xb0 + wb0; acc11 = fminf(fminf(acc11, t.x), t.y);
            t = xb1 + wb1; acc11 = fminf(fminf(acc11, t.x), t.y);
        }
        __syncthreads();
    }

    // ---- epilogue: two float2 stores per thread ----
    {
        v2f v0 = {acc00, acc01};
        *(v2f*)&out[(size_t)(b0 + rb + 0) * OUT_ + o0 + ro] = v0;
        v2f v1 = {acc10, acc11};
        *(v2f*)&out[(size_t)(b0 + rb + 1) * OUT_ + o0 + ro] = v1;
    }
}

extern "C" void kernel_launch(void* const* d_in, const int* in_sizes, int n_in,
                              void* d_out, int out_size, void* d_ws, size_t ws_size,
                              hipStream_t stream) {
    const float* x = (const float*)d_in[0];   // [512, 512]
    const float* w = (const float*)d_in[1];   // [1024, 512]
    float* out = (float*)d_out;               // [512, 1024]

    dim3 grid(B_ / TB, OUT_ / TO);            // 16 x 32 = 512 blocks, 2/CU
    tropical_kernel<<<grid, 256, 0, stream>>>(x, w, out);
}